// Round 1
// baseline (808.239 us; speedup 1.0000x reference)
//
#include <hip/hip_runtime.h>
#include <stdint.h>

// ---------------------------------------------------------------------------
// ODEFunc: relu -> conv3x3(SAME) -> [pool8x8 -> MLP(pruned w1,w2) -> upsample]
//          -> instance_norm
// Key identities exploited:
//  * conv feeds ONLY a 4x4 avgpool => fold pool into conv: 9-shift box sums of
//    relu(x) then GEMM [2048 x 256 x K=2304]  (16x fewer FLOPs than conv)
//  * upsample is 4x4 replication => instance norm computed on the 8x8 grid
//  * prune threshold = exact 90th percentile via sampled range + one exact
//    1-ULP-resolution histogram pass (f32 bit patterns of |w| are monotone)
// ---------------------------------------------------------------------------

typedef float f32x4 __attribute__((ext_vector_type(4)));
typedef __bf16 bf16x8 __attribute__((ext_vector_type(8)));

#define NBATCH 32
#define NCH    256
#define NNODE  16384
#define FEATD  2048
#define KCONV  2304

static constexpr long long NW   = 33554432LL;           // elems in w1 / w2
static constexpr double    POS_D = 0.9 * (double)(NW - 1);
static constexpr int       K0    = (int)POS_D;          // 30198987

// workspace layout (bytes)
static constexpr size_t OFF_APOOL = 0;                  // 2048*2304*2 bf16
static constexpr size_t OFF_NODES = 9437184;            // 32*16384*2 bf16
static constexpr size_t OFF_HF32  = 10485760;           // 2048*32*4  f32
static constexpr size_t OFF_HB    = 10747904;           // 32*2048*2  bf16
static constexpr size_t OFF_G     = 10878976;           // 16384*32*4 f32
static constexpr size_t OFF_SHIST = 12976128;           // 4096*4
static constexpr size_t OFF_CTRL  = 12992512;           // 2*64
static constexpr size_t OFF_BSUMS = 12992768;           // 256*4
static constexpr size_t OFF_FINE  = 12993792;           // 8*524288*4
static constexpr size_t WS_NEEDED = OFF_FINE + 8ull * 524288ull * 4ull;

struct Ctrl {
  unsigned bin_lo, nbins, below, pad;
  float thr, a, b;
  unsigned dbg;
};

__device__ __forceinline__ float prune1(float v, float thr) {
  return fabsf(v) >= thr ? v : 0.0f;
}

// ---------------- percentile pipeline ----------------

// 512 blocks: each reads 1024 contiguous floats (chunked deterministic sample,
// m = 524288), coarse histogram of |w| bit pattern bits 30..19.
__global__ void k_sample_hist(const float* __restrict__ w, unsigned* __restrict__ hist) {
  __shared__ unsigned lh[4096];
  int t = threadIdx.x;
  for (int i = t; i < 4096; i += 256) lh[i] = 0;
  __syncthreads();
  const float4* p = (const float4*)(w + (size_t)blockIdx.x * 65536);
  float4 v = p[t];
  {
    unsigned k;
    k = (__float_as_uint(v.x) & 0x7fffffffu) >> 19; atomicAdd(&lh[k], 1u);
    k = (__float_as_uint(v.y) & 0x7fffffffu) >> 19; atomicAdd(&lh[k], 1u);
    k = (__float_as_uint(v.z) & 0x7fffffffu) >> 19; atomicAdd(&lh[k], 1u);
    k = (__float_as_uint(v.w) & 0x7fffffffu) >> 19; atomicAdd(&lh[k], 1u);
  }
  __syncthreads();
  for (int i = t; i < 4096; i += 256)
    if (lh[i]) atomicAdd(&hist[i], lh[i]);
}

// pick a conservative coarse-bin range [bin_lo, bin_lo+nbins) around the 90th
// percentile of the sample (+-50 sigma of binomial rank noise, +1 guard bin).
__global__ void k_range_select(const unsigned* __restrict__ hist, Ctrl* __restrict__ c) {
  __shared__ unsigned csum[256];
  __shared__ unsigned pre[256];
  __shared__ unsigned res[3];
  int t = threadIdx.x;
  unsigned loc[16];
  unsigned s = 0;
  for (int i = 0; i < 16; ++i) { loc[i] = hist[t * 16 + i]; s += loc[i]; }
  csum[t] = s;
  __syncthreads();
  if (t == 0) {
    unsigned acc = 0;
    for (int i = 0; i < 256; ++i) { pre[i] = acc; acc += csum[i]; }
  }
  __syncthreads();
  const int m = 524288, qm = 471859, MR = 10850;   // 50 sigma margin
  int targ[3] = { qm - MR, qm, qm + MR };
  for (int k = 0; k < 3; ++k) {
    int r = targ[k];
    if (r < 0) r = 0;
    if (r >= m) r = m - 1;
    if ((int)pre[t] <= r && r < (int)(pre[t] + csum[t])) {
      unsigned acc = pre[t];
      for (int i = 0; i < 16; ++i) {
        acc += loc[i];
        if ((int)acc > r) { res[k] = (unsigned)(t * 16 + i); break; }
      }
    }
  }
  __syncthreads();
  if (t == 0) {
    int lo = (int)res[0] - 1; if (lo < 0) lo = 0;
    int hi = (int)res[2] + 1; if (hi > 4095) hi = 4095;
    int nb = hi - lo + 1;
    if (nb > 8) {                    // safety clamp, should not trigger
      int bq = (int)res[1];
      lo = bq - 3; if (lo < 0) lo = 0;
      nb = 8; if (lo + nb > 4096) lo = 4096 - nb;
    }
    c->bin_lo = (unsigned)lo;
    c->nbins  = (unsigned)nb;
    c->below  = 0;
    c->thr    = 0.f;
  }
}

// full pass: count elements below range; 1-ULP histogram inside range.
__global__ void k_exact_hist(const float* __restrict__ w, unsigned* __restrict__ fine,
                             Ctrl* __restrict__ c) {
  int t = threadIdx.x;
  unsigned lo = c->bin_lo, nb = c->nbins;
  unsigned below = 0;
  const float4* p = (const float4*)(w + (size_t)blockIdx.x * 32768);
  for (int it = 0; it < 32; ++it) {
    float4 v = p[it * 256 + t];
    float comps[4] = { v.x, v.y, v.z, v.w };
#pragma unroll
    for (int j = 0; j < 4; ++j) {
      unsigned key = __float_as_uint(comps[j]) & 0x7fffffffu;
      unsigned cb = key >> 19;
      if (cb < lo) below++;
      else {
        unsigned d = cb - lo;
        if (d < nb) atomicAdd(&fine[(d << 19) | (key & 0x7ffffu)], 1u);
      }
    }
  }
  for (int off = 1; off < 64; off <<= 1) below += __shfl_xor(below, off);
  if ((t & 63) == 0) atomicAdd(&c->below, below);
}

// per-block sums of the fine histogram (256 blocks x 16384 bins)
__global__ void k_fine_sum(const unsigned* __restrict__ fine, unsigned* __restrict__ bs) {
  int t = threadIdx.x;
  const uint4* p = (const uint4*)(fine + (size_t)blockIdx.x * 16384);
  unsigned s = 0;
  for (int k = 0; k < 16; ++k) {
    uint4 u = p[k * 256 + t];
    s += u.x + u.y + u.z + u.w;
  }
  for (int off = 1; off < 64; off <<= 1) s += __shfl_xor(s, off);
  __shared__ unsigned r[4];
  if ((t & 63) == 0) r[t >> 6] = s;
  __syncthreads();
  if (t == 0) bs[blockIdx.x] = r[0] + r[1] + r[2] + r[3];
}

// locate order statistics a[K0], a[K0+1]; lerp -> threshold
__global__ void k_fine_select(const unsigned* __restrict__ fine, const unsigned* __restrict__ bs,
                              Ctrl* __restrict__ c, double frac) {
  __shared__ unsigned bpre[257];
  __shared__ unsigned cs[256];
  __shared__ unsigned cpre[257];
  __shared__ unsigned resbits[2];
  __shared__ int bi_s;
  int t = threadIdx.x;
  if (t == 0) {
    unsigned acc = 0;
    for (int i = 0; i < 256; ++i) { bpre[i] = acc; acc += bs[i]; }
    bpre[256] = acc;
  }
  __syncthreads();
  long long total = (long long)bpre[256];
  long long below = (long long)c->below;
  for (int k = 0; k < 2; ++k) {
    long long r = (long long)(K0 + k) - below;
    if (r < 0) r = 0;
    if (r >= total) r = total - 1;
    if (t == 0) {
      int bi = 0;
      for (int i = 0; i < 256; ++i)
        if ((long long)bpre[i] <= r && r < (long long)bpre[i + 1]) { bi = i; break; }
      bi_s = bi;
    }
    __syncthreads();
    int bi = bi_s;
    size_t base = (size_t)bi * 16384 + (size_t)t * 64;
    unsigned s = 0;
    for (int i = 0; i < 64; ++i) s += fine[base + i];
    cs[t] = s;
    __syncthreads();
    if (t == 0) {
      unsigned acc = bpre[bi];
      for (int i = 0; i < 256; ++i) { cpre[i] = acc; acc += cs[i]; }
      cpre[256] = acc;
    }
    __syncthreads();
    if ((long long)cpre[t] <= r && r < (long long)cpre[t] + (long long)cs[t]) {
      unsigned acc = cpre[t];
      for (int i = 0; i < 64; ++i) {
        acc += fine[base + i];
        if ((long long)acc > r) {
          unsigned fi = (unsigned)(base + i);
          resbits[k] = ((c->bin_lo + (fi >> 19)) << 19) | (fi & 0x7ffffu);
          break;
        }
      }
    }
    __syncthreads();
  }
  if (t == 0) {
    double a = (double)__uint_as_float(resbits[0]);
    double b = (double)__uint_as_float(resbits[1]);
    c->a = (float)a; c->b = (float)b;
    c->thr = (float)(a + frac * (b - a));
  }
}

// ---------------- compute pipeline ----------------

// relu(x) -> nine shifted 4x4 box sums (the pooled conv taps), bf16 out.
// one wave per (b, c') plane; 4 planes per block.
__global__ void k_pool(const float* __restrict__ x, __bf16* __restrict__ apool) {
  __shared__ float lds[4][1024];
  __shared__ float V[4][24][32];
  int t = threadIdx.x, wv = t >> 6, lane = t & 63;
  int p = blockIdx.x * 4 + wv;          // plane id: b*256 + c'
  int b = p >> 8, cch = p & 255;
  const float* xp = x + (size_t)p * 1024;
  for (int q = 0; q < 4; ++q) {
    float4 v = ((const float4*)xp)[q * 64 + lane];
    int idx = (q * 64 + lane) * 4;
    lds[wv][idx + 0] = fmaxf(v.x, 0.f);
    lds[wv][idx + 1] = fmaxf(v.y, 0.f);
    lds[wv][idx + 2] = fmaxf(v.z, 0.f);
    lds[wv][idx + 3] = fmaxf(v.w, 0.f);
  }
  __syncthreads();
  // vertical 4-row sums at starts r0 = 4i + dy - 1 (zero pad OOB)
  for (int e = lane; e < 768; e += 64) {
    int vi = e >> 5, ccol = e & 31;
    int i = vi / 3, dy = vi % 3;
    int r0 = 4 * i + dy - 1;
    float s = 0.f;
#pragma unroll
    for (int u = 0; u < 4; ++u) {
      int r = r0 + u;
      if (r >= 0 && r < 32) s += lds[wv][r * 32 + ccol];
    }
    V[wv][vi][ccol] = s;
  }
  __syncthreads();
  int pos = lane, i = pos >> 3, j = pos & 7;
  __bf16* ap = apool + (size_t)(b * 64 + pos) * KCONV + cch * 9;
#pragma unroll
  for (int dy = 0; dy < 3; ++dy) {
    int vi = i * 3 + dy;
#pragma unroll
    for (int dx = 0; dx < 3; ++dx) {
      int c0 = 4 * j + dx - 1;
      float s = 0.f;
#pragma unroll
      for (int v4 = 0; v4 < 4; ++v4) {
        int cc = c0 + v4;
        if (cc >= 0 && cc < 32) s += V[wv][vi][cc];
      }
      ap[dy * 3 + dx] = (__bf16)(s * 0.0625f);
    }
  }
}

// pooled conv as GEMM: nodes[b, c*64+pos] = sum_K conv_w[c,K] * apool[row,K]
// M = channels (A from conv_w, cvt bf16), N = rows (B from apool), K = 2304.
__global__ void k_convgemm(const __bf16* __restrict__ apool, const float* __restrict__ cw,
                           __bf16* __restrict__ nodes) {
  int t = threadIdx.x, wv = t >> 6, l = t & 63;
  int cb = blockIdx.x & 15;        // 16-channel tile
  int rg = blockIdx.x >> 4;        // 256-row group
  int row0 = rg * 256 + wv * 64;
  int cbase = cb * 16;
  int kofs = (l >> 4) * 8;
  f32x4 acc[4] = {};
  const float* aw = cw + (size_t)(cbase + (l & 15)) * KCONV + kofs;
  for (int kk = 0; kk < KCONV; kk += 32) {
    float4 a0 = *(const float4*)(aw + kk);
    float4 a1 = *(const float4*)(aw + kk + 4);
    bf16x8 af;
    af[0] = (__bf16)a0.x; af[1] = (__bf16)a0.y; af[2] = (__bf16)a0.z; af[3] = (__bf16)a0.w;
    af[4] = (__bf16)a1.x; af[5] = (__bf16)a1.y; af[6] = (__bf16)a1.z; af[7] = (__bf16)a1.w;
#pragma unroll
    for (int rt = 0; rt < 4; ++rt) {
      const __bf16* bp = apool + (size_t)(row0 + rt * 16 + (l & 15)) * KCONV + kk + kofs;
      bf16x8 bv = *(const bf16x8*)bp;
      acc[rt] = __builtin_amdgcn_mfma_f32_16x16x32_bf16(af, bv, acc[rt], 0, 0, 0);
    }
  }
#pragma unroll
  for (int rt = 0; rt < 4; ++rt) {
    int prow = row0 + rt * 16 + (l & 15);
    int bidx = prow >> 6, pos = prow & 63;
#pragma unroll
    for (int j = 0; j < 4; ++j) {
      int cc = cbase + (l >> 4) * 4 + j;
      nodes[(size_t)bidx * NNODE + cc * 64 + pos] = (__bf16)acc[rt][j];
    }
  }
}

// h_partial[f, b] += sum_k prune(w1[f,k]) * nodes[b,k];  K split 32 ways.
__global__ void k_gemm1(const float* __restrict__ w1, const __bf16* __restrict__ nodes,
                        const Ctrl* __restrict__ ctrl, float* __restrict__ hf) {
  int t = threadIdx.x, wv = t >> 6, l = t & 63;
  int fb = blockIdx.x >> 5;        // 32 feature blocks of 64
  int ks = blockIdx.x & 31;        // K chunk of 512
  float thr = ctrl->thr;
  int kofs = (l >> 4) * 8;
  int kk0 = ks * 512;
  const float*  awp = w1 + (size_t)(fb * 64 + wv * 16 + (l & 15)) * NNODE + kk0 + kofs;
  const __bf16* b0p = nodes + (size_t)(l & 15) * NNODE + kk0 + kofs;
  const __bf16* b1p = nodes + (size_t)((l & 15) + 16) * NNODE + kk0 + kofs;
  f32x4 acc0 = {}, acc1 = {};
#pragma unroll 4
  for (int kk = 0; kk < 512; kk += 32) {
    float4 a0 = *(const float4*)(awp + kk);
    float4 a1 = *(const float4*)(awp + kk + 4);
    bf16x8 af;
    af[0] = (__bf16)prune1(a0.x, thr); af[1] = (__bf16)prune1(a0.y, thr);
    af[2] = (__bf16)prune1(a0.z, thr); af[3] = (__bf16)prune1(a0.w, thr);
    af[4] = (__bf16)prune1(a1.x, thr); af[5] = (__bf16)prune1(a1.y, thr);
    af[6] = (__bf16)prune1(a1.z, thr); af[7] = (__bf16)prune1(a1.w, thr);
    bf16x8 bv0 = *(const bf16x8*)(b0p + kk);
    bf16x8 bv1 = *(const bf16x8*)(b1p + kk);
    acc0 = __builtin_amdgcn_mfma_f32_16x16x32_bf16(af, bv0, acc0, 0, 0, 0);
    acc1 = __builtin_amdgcn_mfma_f32_16x16x32_bf16(af, bv1, acc1, 0, 0, 0);
  }
#pragma unroll
  for (int j = 0; j < 4; ++j) {
    int f = fb * 64 + wv * 16 + (l >> 4) * 4 + j;
    atomicAdd(&hf[f * 32 + (l & 15)], acc0[j]);
    atomicAdd(&hf[f * 32 + 16 + (l & 15)], acc1[j]);
  }
}

// relu + transpose + bf16 for GEMM2's B operand
__global__ void k_relucvt(const float* __restrict__ hf, __bf16* __restrict__ hb) {
  int idx = blockIdx.x * 256 + threadIdx.x;   // 65536
  float v = fmaxf(hf[idx], 0.f);
  int f = idx >> 5, b = idx & 31;
  hb[b * FEATD + f] = (__bf16)v;
}

// g[n, b] += sum_f prune(w2[n,f]) * h[b,f];  K split 4 ways.
__global__ void k_gemm2(const float* __restrict__ w2, const __bf16* __restrict__ hb,
                        const Ctrl* __restrict__ ctrl, float* __restrict__ g) {
  int t = threadIdx.x, wv = t >> 6, l = t & 63;
  int nb = blockIdx.x >> 2;        // 256 row blocks of 64
  int ks = blockIdx.x & 3;         // K chunk of 512
  float thr = ctrl->thr;
  int kofs = (l >> 4) * 8;
  int kk0 = ks * 512;
  const float*  awp = w2 + (size_t)(nb * 64 + wv * 16 + (l & 15)) * FEATD + kk0 + kofs;
  const __bf16* b0p = hb + (size_t)(l & 15) * FEATD + kk0 + kofs;
  const __bf16* b1p = hb + (size_t)((l & 15) + 16) * FEATD + kk0 + kofs;
  f32x4 acc0 = {}, acc1 = {};
#pragma unroll 4
  for (int kk = 0; kk < 512; kk += 32) {
    float4 a0 = *(const float4*)(awp + kk);
    float4 a1 = *(const float4*)(awp + kk + 4);
    bf16x8 af;
    af[0] = (__bf16)prune1(a0.x, thr); af[1] = (__bf16)prune1(a0.y, thr);
    af[2] = (__bf16)prune1(a0.z, thr); af[3] = (__bf16)prune1(a0.w, thr);
    af[4] = (__bf16)prune1(a1.x, thr); af[5] = (__bf16)prune1(a1.y, thr);
    af[6] = (__bf16)prune1(a1.z, thr); af[7] = (__bf16)prune1(a1.w, thr);
    bf16x8 bv0 = *(const bf16x8*)(b0p + kk);
    bf16x8 bv1 = *(const bf16x8*)(b1p + kk);
    acc0 = __builtin_amdgcn_mfma_f32_16x16x32_bf16(af, bv0, acc0, 0, 0, 0);
    acc1 = __builtin_amdgcn_mfma_f32_16x16x32_bf16(af, bv1, acc1, 0, 0, 0);
  }
#pragma unroll
  for (int j = 0; j < 4; ++j) {
    int n = nb * 64 + wv * 16 + (l >> 4) * 4 + j;
    atomicAdd(&g[n * 32 + (l & 15)], acc0[j]);
    atomicAdd(&g[n * 32 + 16 + (l & 15)], acc1[j]);
  }
}

// instance norm on the 8x8 grid (== norm of the upsampled map) + 4x upsample
__global__ void k_normup(const float* __restrict__ g, const float* __restrict__ gamma,
                         const float* __restrict__ beta, float* __restrict__ out) {
  int t = threadIdx.x, wv = t >> 6, lane = t & 63;
  int id = blockIdx.x * 4 + wv;         // b*256 + c
  int b = id >> 8, cch = id & 255;
  float v = g[(size_t)(cch * 64 + lane) * 32 + b];
  float s = v;
  for (int off = 1; off < 64; off <<= 1) s += __shfl_xor(s, off);
  float mean = s * (1.0f / 64.0f);
  float d = v - mean;
  float q = d * d;
  for (int off = 1; off < 64; off <<= 1) q += __shfl_xor(q, off);
  float var = q * (1.0f / 64.0f);
  float y = d * rsqrtf(var + 1e-5f) * gamma[cch] + beta[cch];
  int i = lane >> 3, j = lane & 7;
  float4 y4 = { y, y, y, y };
  float* op = out + ((size_t)(b * 256 + cch) * 32 + i * 4) * 32 + j * 4;
#pragma unroll
  for (int u = 0; u < 4; ++u) *(float4*)(op + u * 32) = y4;
}

// ---------------------------------------------------------------------------

extern "C" void kernel_launch(void* const* d_in, const int* in_sizes, int n_in,
                              void* d_out, int out_size, void* d_ws, size_t ws_size,
                              hipStream_t stream) {
  const float* x      = (const float*)d_in[0];
  const float* conv_w = (const float*)d_in[1];
  const float* w1     = (const float*)d_in[2];
  const float* w2     = (const float*)d_in[3];
  const float* gamma  = (const float*)d_in[4];
  const float* beta   = (const float*)d_in[5];
  float* out = (float*)d_out;

  if (ws_size < WS_NEEDED) return;   // fail loudly via wrong output

  char* wsb = (char*)d_ws;
  __bf16*   apool = (__bf16*)(wsb + OFF_APOOL);
  __bf16*   nodes = (__bf16*)(wsb + OFF_NODES);
  float*    hf    = (float*)(wsb + OFF_HF32);
  __bf16*   hb    = (__bf16*)(wsb + OFF_HB);
  float*    g     = (float*)(wsb + OFF_G);
  unsigned* shist = (unsigned*)(wsb + OFF_SHIST);
  Ctrl*     ctrl  = (Ctrl*)(wsb + OFF_CTRL);
  unsigned* bsums = (unsigned*)(wsb + OFF_BSUMS);
  unsigned* fine  = (unsigned*)(wsb + OFF_FINE);

  const double frac = POS_D - (double)K0;
  const float* wm[2] = { w1, w2 };
  for (int m = 0; m < 2; ++m) {
    Ctrl* c = ctrl + m;
    hipMemsetAsync(shist, 0, 4096 * 4, stream);
    k_sample_hist<<<512, 256, 0, stream>>>(wm[m], shist);
    k_range_select<<<1, 256, 0, stream>>>(shist, c);
    hipMemsetAsync(fine, 0, 8ull * 524288ull * 4ull, stream);
    k_exact_hist<<<1024, 256, 0, stream>>>(wm[m], fine, c);
    k_fine_sum<<<256, 256, 0, stream>>>(fine, bsums);
    k_fine_select<<<1, 256, 0, stream>>>(fine, bsums, c, frac);
  }

  k_pool<<<2048, 256, 0, stream>>>(x, apool);
  k_convgemm<<<128, 256, 0, stream>>>(apool, conv_w, nodes);

  hipMemsetAsync(hf, 0, 2048 * 32 * 4, stream);
  k_gemm1<<<1024, 256, 0, stream>>>(w1, nodes, ctrl + 0, hf);
  k_relucvt<<<256, 256, 0, stream>>>(hf, hb);

  hipMemsetAsync(g, 0, 16384 * 32 * 4, stream);
  k_gemm2<<<1024, 256, 0, stream>>>(w2, hb, ctrl + 1, g);

  k_normup<<<2048, 256, 0, stream>>>(g, gamma, beta, out);
}